// Round 1
// baseline (76.107 us; speedup 1.0000x reference)
//
#include <hip/hip_runtime.h>
#include <math.h>

// Problem constants (FOAA_SA, attention_type='OA', per-head dim 1)
#define BB 4
#define SS 1024
#define DD 32
#define HH 32

// Online-softmax state merge: (m,s,w) <- merge((m,s,w),(m2,s2,w2))
__device__ __forceinline__ void sm_merge(float& m, float& s, float& w,
                                         float m2, float s2, float w2) {
    float nm = fmaxf(m, m2);
    float a1 = __expf(m - nm);
    float a2 = __expf(m2 - nm);
    s = s * a1 + s2 * a2;
    w = w * a1 + w2 * a2;
    m = nm;
}

// Kernel A: one block per (b,h). Computes
//   c[b,h] = sum_j softmax_j(K[b,j,h]) * V[b,j,h]
// where K[b,j,h] = x[b,j,:]·Wk[h,:] + bk[h], V likewise.
// (softmax over j of Q_i+K_j is independent of Q_i, so Q is never needed.)
__global__ __launch_bounds__(256) void kv_softmax_kernel(
    const float* __restrict__ x,
    const float* __restrict__ Wk, const float* __restrict__ bk,
    const float* __restrict__ Wv, const float* __restrict__ bv,
    float* __restrict__ c_out)
{
    const int bid = blockIdx.x;
    const int b = bid >> 5;   // / HH
    const int h = bid & 31;   // % HH
    const int tid = threadIdx.x;

    __shared__ float wk[DD], wv[DD];
    __shared__ float red_m[4], red_s[4], red_w[4];

    if (tid < DD)            wk[tid]      = Wk[h * DD + tid];
    else if (tid < 2 * DD)   wv[tid - DD] = Wv[h * DD + (tid - DD)];
    __syncthreads();

    const float bkh = bk[h];
    const float bvh = bv[h];

    float m = -INFINITY, s = 0.f, w = 0.f;
    const float* xb = x + (size_t)b * SS * DD;

    // 4 rows per thread (SS=1024, 256 threads)
    for (int j = tid; j < SS; j += 256) {
        const float4* row = (const float4*)(xb + (size_t)j * DD);
        float kd = 0.f, vd = 0.f;
        #pragma unroll
        for (int q = 0; q < 8; ++q) {
            float4 v4 = row[q];
            kd += v4.x * wk[4*q+0] + v4.y * wk[4*q+1] + v4.z * wk[4*q+2] + v4.w * wk[4*q+3];
            vd += v4.x * wv[4*q+0] + v4.y * wv[4*q+1] + v4.z * wv[4*q+2] + v4.w * wv[4*q+3];
        }
        float kk = kd + bkh;
        float vv = vd + bvh;
        float nm = fmaxf(m, kk);
        float a  = __expf(m - nm);   // m=-inf first iter -> a=0
        float e  = __expf(kk - nm);
        s = s * a + e;
        w = w * a + e * vv;
        m = nm;
    }

    // wave64 butterfly reduce of (m,s,w)
    #pragma unroll
    for (int off = 32; off >= 1; off >>= 1) {
        float m2 = __shfl_xor(m, off);
        float s2 = __shfl_xor(s, off);
        float w2 = __shfl_xor(w, off);
        sm_merge(m, s, w, m2, s2, w2);
    }
    const int wave = tid >> 6;
    if ((tid & 63) == 0) { red_m[wave] = m; red_s[wave] = s; red_w[wave] = w; }
    __syncthreads();
    if (tid == 0) {
        float M = red_m[0], Sv = red_s[0], W = red_w[0];
        #pragma unroll
        for (int i = 1; i < 4; ++i) sm_merge(M, Sv, W, red_m[i], red_s[i], red_w[i]);
        c_out[b * HH + h] = W / Sv;
    }
}

// Kernel B: out[b,i,d] = bo[d] + sum_h c[b,h]*Wo[d,h], identical for every i.
// Grid: 32 blocks per batch, each block writes 32 rows.
__global__ __launch_bounds__(256) void project_bcast_kernel(
    const float* __restrict__ c, const float* __restrict__ Wo,
    const float* __restrict__ bo, float* __restrict__ out)
{
    const int bid = blockIdx.x;
    const int b = bid >> 5;
    const int chunk = bid & 31;          // rows [chunk*32, chunk*32+32)
    const int tid = threadIdx.x;

    __shared__ float cs[HH];
    if (tid < HH) cs[tid] = c[b * HH + tid];
    __syncthreads();

    const int d = tid & 31;
    const int r = tid >> 5;              // 0..7
    float p = bo[d];
    #pragma unroll
    for (int hh = 0; hh < HH; ++hh) p += cs[hh] * Wo[d * HH + hh];

    float* ob = out + ((size_t)b * SS + (size_t)chunk * 32) * DD;
    #pragma unroll
    for (int k = 0; k < 4; ++k) {
        ob[(size_t)(r + k * 8) * DD + d] = p;   // 64 consecutive floats per wave: coalesced
    }
}

extern "C" void kernel_launch(void* const* d_in, const int* in_sizes, int n_in,
                              void* d_out, int out_size, void* d_ws, size_t ws_size,
                              hipStream_t stream) {
    const float* x  = (const float*)d_in[0];
    // d_in[1] = Wq, d_in[2] = bq: mathematically dead (softmax over j cancels Q_i)
    const float* Wk = (const float*)d_in[3];
    const float* bk = (const float*)d_in[4];
    const float* Wv = (const float*)d_in[5];
    const float* bv = (const float*)d_in[6];
    const float* Wo = (const float*)d_in[7];
    const float* bo = (const float*)d_in[8];
    float* out  = (float*)d_out;
    float* c_ws = (float*)d_ws;          // BB*HH = 128 floats

    kv_softmax_kernel<<<BB * HH, 256, 0, stream>>>(x, Wk, bk, Wv, bv, c_ws);
    project_bcast_kernel<<<BB * 32, 256, 0, stream>>>(c_ws, Wo, bo, out);
}